// Round 3
// baseline (640.097 us; speedup 1.0000x reference)
//
#include <hip/hip_runtime.h>
#include <math.h>

#define NB 2
#define NQ 2048
#define NK 2048
#define NH 8
#define NC 32
#define NHC 256
#define NCIN 256

__device__ __forceinline__ float redmax16(float v) {
    v = fmaxf(v, __shfl_xor(v, 1, 16));
    v = fmaxf(v, __shfl_xor(v, 2, 16));
    v = fmaxf(v, __shfl_xor(v, 4, 16));
    v = fmaxf(v, __shfl_xor(v, 8, 16));
    return v;
}
__device__ __forceinline__ float redsum16(float v) {
    v += __shfl_xor(v, 1, 16);
    v += __shfl_xor(v, 2, 16);
    v += __shfl_xor(v, 4, 16);
    v += __shfl_xor(v, 8, 16);
    return v;
}

// 64x64 tile fp32 GEMM body: C[m0:m0+64, n0:n0+64] = A[.,0:256] @ W[0:256,.]
// 256 threads (16x16), 4x4 accumulators per thread.
__device__ __forceinline__ void gemm_tile(const float* __restrict__ A,
                                          const float* __restrict__ W,
                                          float (*__restrict__ As)[68],
                                          float (*__restrict__ Bs)[68],
                                          float acc[4][4], int m0, int n0)
{
    const int t = threadIdx.x;
    const int ty = t >> 4, tx = t & 15;
    const int arow = t >> 2, acol = (t & 3) * 8;   // A staging: 64 rows x 32 cols
    const int brow = t >> 3, bcol = (t & 7) * 8;   // B staging: 32 rows x 64 cols

    for (int k0 = 0; k0 < NCIN; k0 += 32) {
        float4 a0 = *(const float4*)&A[(size_t)(m0 + arow) * NCIN + k0 + acol];
        float4 a1 = *(const float4*)&A[(size_t)(m0 + arow) * NCIN + k0 + acol + 4];
        float4 b0 = *(const float4*)&W[(size_t)(k0 + brow) * NHC + n0 + bcol];
        float4 b1 = *(const float4*)&W[(size_t)(k0 + brow) * NHC + n0 + bcol + 4];
        __syncthreads();   // previous iteration's LDS reads are done
        As[acol + 0][arow] = a0.x; As[acol + 1][arow] = a0.y;
        As[acol + 2][arow] = a0.z; As[acol + 3][arow] = a0.w;
        As[acol + 4][arow] = a1.x; As[acol + 5][arow] = a1.y;
        As[acol + 6][arow] = a1.z; As[acol + 7][arow] = a1.w;
        *(float4*)&Bs[brow][bcol]     = b0;
        *(float4*)&Bs[brow][bcol + 4] = b1;
        __syncthreads();
        #pragma unroll
        for (int kk = 0; kk < 32; ++kk) {
            float4 av = *(const float4*)&As[kk][ty * 4];
            float4 bv = *(const float4*)&Bs[kk][tx * 4];
            float a_[4] = {av.x, av.y, av.z, av.w};
            float b_[4] = {bv.x, bv.y, bv.z, bv.w};
            #pragma unroll
            for (int i = 0; i < 4; ++i)
                #pragma unroll
                for (int j = 0; j < 4; ++j)
                    acc[i][j] = fmaf(a_[i], b_[j], acc[i][j]);
        }
    }
}

// Projection kernel: z = mode (0:q scaled, 1:k, 2:v, 3:g sigmoid). Output in
// head-split layout [B,H,L,C].
__global__ __launch_bounds__(256) void proj_kernel(
    const float* __restrict__ q_x, const float* __restrict__ kv_x,
    const float* __restrict__ Wq, const float* __restrict__ Wk,
    const float* __restrict__ Wv, const float* __restrict__ Wg,
    const float* __restrict__ bg,
    float* __restrict__ qh, float* __restrict__ kh,
    float* __restrict__ vh, float* __restrict__ gh)
{
    __shared__ float As[32][68];
    __shared__ float Bs[32][68];
    const int mode = blockIdx.z;
    const float* A = (mode == 0 || mode == 3) ? q_x : kv_x;
    const float* W = (mode == 0) ? Wq : (mode == 1) ? Wk : (mode == 2) ? Wv : Wg;
    float* out = (mode == 0) ? qh : (mode == 1) ? kh : (mode == 2) ? vh : gh;
    const int m0 = blockIdx.x * 64, n0 = blockIdx.y * 64;

    float acc[4][4] = {};
    gemm_tile(A, W, As, Bs, acc, m0, n0);

    const int t = threadIdx.x, ty = t >> 4, tx = t & 15;
    #pragma unroll
    for (int i = 0; i < 4; ++i) {
        const int m = m0 + ty * 4 + i;
        const int b = m >> 11, l = m & 2047;
        const int n = n0 + tx * 4;
        const int h = n >> 5, c = n & 31;
        float v[4];
        #pragma unroll
        for (int j = 0; j < 4; ++j) v[j] = acc[i][j];
        if (mode == 0) {
            #pragma unroll
            for (int j = 0; j < 4; ++j) v[j] *= 0.17677669529663687f; // C^-0.5
        } else if (mode == 3) {
            #pragma unroll
            for (int j = 0; j < 4; ++j)
                v[j] = 1.0f / (1.0f + __expf(-(v[j] + bg[n + j])));
        }
        float4 vv; vv.x = v[0]; vv.y = v[1]; vv.z = v[2]; vv.w = v[3];
        *(float4*)&out[((size_t)(b * NH + h) * NQ + l) * NC + c] = vv;
    }
}

// Output projection: out = og @ Wo + bo, flat [B*Q, 256].
__global__ __launch_bounds__(256) void out_proj_kernel(
    const float* __restrict__ og, const float* __restrict__ Wo,
    const float* __restrict__ bo, float* __restrict__ out)
{
    __shared__ float As[32][68];
    __shared__ float Bs[32][68];
    const int m0 = blockIdx.x * 64, n0 = blockIdx.y * 64;
    float acc[4][4] = {};
    gemm_tile(og, Wo, As, Bs, acc, m0, n0);
    const int t = threadIdx.x, ty = t >> 4, tx = t & 15;
    #pragma unroll
    for (int i = 0; i < 4; ++i) {
        const int m = m0 + ty * 4 + i;
        const int n = n0 + tx * 4;
        float4 bv = *(const float4*)&bo[n];
        float4 vv;
        vv.x = acc[i][0] + bv.x; vv.y = acc[i][1] + bv.y;
        vv.z = acc[i][2] + bv.z; vv.w = acc[i][3] + bv.w;
        *(float4*)&out[(size_t)m * NHC + n] = vv;
    }
}

// Flash attention with additive pair biases + gating epilogue.
// One block = 64 q-rows of one (b,h). 256 threads (16x16).
// ALL global streams are register-pipelined one full K-tile ahead:
//   k/v     (16 KB/blk/iter) -> consumed at next iter's staging
//   bias1/2 (32 KB/blk/iter, 2/3 of total HBM traffic) -> consumed at next
//           iter's softmax. One-iteration distance ~= 9.6k cyc at the
//           HBM-bound iteration rate, covering queued-HBM latency; issuing
//           them in-iteration (prev version) left only ~2-3k cyc of cover.
__global__ __launch_bounds__(256) void attn_kernel(
    const float* __restrict__ qh, const float* __restrict__ kh,
    const float* __restrict__ vh, const float* __restrict__ gh,
    const float* __restrict__ b1, const float* __restrict__ b2,
    float* __restrict__ og)
{
    __shared__ float qT[32][68];   // q transposed: [c][row]
    __shared__ float kT[32][68];   // k transposed: [c][col]
    __shared__ float vs[64][36];   // v row-major: [k][c]
    __shared__ float pT[64][68];   // p transposed: [k][row]

    // XCD-aware decode: xcd = blockIdx % 8 (dispatch heuristic); each XCD owns
    // 2 full (b,h) so k/v (1 MB) stays L2-resident across its 32 q-tiles.
    const int wg  = blockIdx.x;
    const int xcd = wg & 7;
    const int idx = wg >> 3;               // 0..63
    const int bh  = xcd * 2 + (idx >> 5);  // 0..15
    const int qt  = idx & 31;
    const int q0  = qt * 64;

    const int t  = threadIdx.x;
    const int ty = t >> 4, tx = t & 15;
    const int sr = t >> 2, sc = (t & 3) * 8;   // staging: 64 rows x 32 cols

    // stage Q tile once (transposed); visible after first in-loop barrier
    {
        const float* qb = qh + ((size_t)bh * NQ + q0) * NC;
        float4 x0 = *(const float4*)&qb[sr * NC + sc];
        float4 x1 = *(const float4*)&qb[sr * NC + sc + 4];
        qT[sc + 0][sr] = x0.x; qT[sc + 1][sr] = x0.y;
        qT[sc + 2][sr] = x0.z; qT[sc + 3][sr] = x0.w;
        qT[sc + 4][sr] = x1.x; qT[sc + 5][sr] = x1.y;
        qT[sc + 6][sr] = x1.z; qT[sc + 7][sr] = x1.w;
    }

    float m_run[4], l_run[4], o_acc[4][2];
    #pragma unroll
    for (int i = 0; i < 4; ++i) {
        m_run[i] = -3.0e38f; l_run[i] = 0.0f;
        o_acc[i][0] = 0.0f; o_acc[i][1] = 0.0f;
    }

    const float* kb = kh + (size_t)bh * NK * NC;
    const float* vb = vh + (size_t)bh * NK * NC;
    const size_t brow0 = (size_t)bh * NQ + q0;

    // ---- prologue: preload tile 0 (k/v + bias) into registers ----
    float4 kx0 = *(const float4*)&kb[(size_t)sr * NC + sc];
    float4 kx1 = *(const float4*)&kb[(size_t)sr * NC + sc + 4];
    float4 vx0 = *(const float4*)&vb[(size_t)sr * NC + sc];
    float4 vx1 = *(const float4*)&vb[(size_t)sr * NC + sc + 4];
    float4 nb1[4], nb2[4];   // "next" bias regs (prefetch landing zone)
    #pragma unroll
    for (int i = 0; i < 4; ++i) {
        const size_t off = (brow0 + ty * 4 + i) * (size_t)NK + tx * 4;
        nb1[i] = *(const float4*)&b1[off];
        nb2[i] = *(const float4*)&b2[off];
    }

    for (int kt = 0; kt < NK / 64; ++kt) {
        const int kk0 = kt * 64;
        __syncthreads();   // prev tile's PV reads (vs/pT) done; iter0: qT ready
        kT[sc + 0][sr] = kx0.x; kT[sc + 1][sr] = kx0.y;
        kT[sc + 2][sr] = kx0.z; kT[sc + 3][sr] = kx0.w;
        kT[sc + 4][sr] = kx1.x; kT[sc + 5][sr] = kx1.y;
        kT[sc + 6][sr] = kx1.z; kT[sc + 7][sr] = kx1.w;
        *(float4*)&vs[sr][sc]     = vx0;
        *(float4*)&vs[sr][sc + 4] = vx1;
        __syncthreads();

        // rotate prefetched bias into "current" regs (pure reg moves;
        // constant indices after unroll -> no scratch)
        float4 cb1[4], cb2[4];
        #pragma unroll
        for (int i = 0; i < 4; ++i) { cb1[i] = nb1[i]; cb2[i] = nb2[i]; }

        // issue NEXT tile's loads (k/v + bias), consumed one full
        // (HBM-bound, ~9.6k cyc) iteration from now
        if (kt + 1 < NK / 64) {
            const size_t noff = (size_t)(kk0 + 64 + sr) * NC + sc;
            kx0 = *(const float4*)&kb[noff];
            kx1 = *(const float4*)&kb[noff + 4];
            vx0 = *(const float4*)&vb[noff];
            vx1 = *(const float4*)&vb[noff + 4];
            #pragma unroll
            for (int i = 0; i < 4; ++i) {
                const size_t off =
                    (brow0 + ty * 4 + i) * (size_t)NK + kk0 + 64 + tx * 4;
                nb1[i] = *(const float4*)&b1[off];
                nb2[i] = *(const float4*)&b2[off];
            }
        }

        // QK^T: s[i][j] over rows 4ty+i, cols 4tx+j
        float s[4][4] = {};
        #pragma unroll
        for (int c = 0; c < 32; ++c) {
            float4 av = *(const float4*)&qT[c][ty * 4];
            float4 kv = *(const float4*)&kT[c][tx * 4];
            float a_[4] = {av.x, av.y, av.z, av.w};
            float k_[4] = {kv.x, kv.y, kv.z, kv.w};
            #pragma unroll
            for (int i = 0; i < 4; ++i)
                #pragma unroll
                for (int j = 0; j < 4; ++j)
                    s[i][j] = fmaf(a_[i], k_[j], s[i][j]);
        }

        // biases + online softmax (row reduce across 16 contiguous lanes)
        float p[4][4];
        #pragma unroll
        for (int i = 0; i < 4; ++i) {
            s[i][0] += cb1[i].x + cb2[i].x;
            s[i][1] += cb1[i].y + cb2[i].y;
            s[i][2] += cb1[i].z + cb2[i].z;
            s[i][3] += cb1[i].w + cb2[i].w;
            float tm = fmaxf(fmaxf(s[i][0], s[i][1]), fmaxf(s[i][2], s[i][3]));
            tm = redmax16(tm);
            const float mn   = fmaxf(m_run[i], tm);
            const float resc = __expf(m_run[i] - mn);
            p[i][0] = __expf(s[i][0] - mn);
            p[i][1] = __expf(s[i][1] - mn);
            p[i][2] = __expf(s[i][2] - mn);
            p[i][3] = __expf(s[i][3] - mn);
            const float tsum = redsum16(p[i][0] + p[i][1] + p[i][2] + p[i][3]);
            l_run[i] = l_run[i] * resc + tsum;
            o_acc[i][0] *= resc; o_acc[i][1] *= resc;
            m_run[i] = mn;
        }
        // transposed p store, vectorized: 4x b128 (~8-way on 4-bank groups,
        // ~25 cyc/iter total — negligible vs the ~9.6k cyc HBM-bound iter)
        #pragma unroll
        for (int j = 0; j < 4; ++j) {
            float4 w;
            w.x = p[0][j]; w.y = p[1][j]; w.z = p[2][j]; w.w = p[3][j];
            *(float4*)&pT[tx * 4 + j][ty * 4] = w;
        }
        __syncthreads();

        // PV: o[4 rows][2 ch], ch = 2tx..2tx+1
        // pT read: 4 distinct addrs x16-lane broadcast (free); vs read:
        // float2 spread over all 32 banks (conflict-free)
        #pragma unroll
        for (int k = 0; k < 64; ++k) {
            float4 p4 = *(const float4*)&pT[k][ty * 4];
            float2 v2 = *(const float2*)&vs[k][tx * 2];
            o_acc[0][0] = fmaf(p4.x, v2.x, o_acc[0][0]);
            o_acc[0][1] = fmaf(p4.x, v2.y, o_acc[0][1]);
            o_acc[1][0] = fmaf(p4.y, v2.x, o_acc[1][0]);
            o_acc[1][1] = fmaf(p4.y, v2.y, o_acc[1][1]);
            o_acc[2][0] = fmaf(p4.z, v2.x, o_acc[2][0]);
            o_acc[2][1] = fmaf(p4.z, v2.y, o_acc[2][1]);
            o_acc[3][0] = fmaf(p4.w, v2.x, o_acc[3][0]);
            o_acc[3][1] = fmaf(p4.w, v2.y, o_acc[3][1]);
        }
        // next iteration's first __syncthreads protects kT/vs/pT overwrite
    }

    // epilogue: normalize, gate, store to og [B, Q, H*C]
    const int b = bh >> 3, h = bh & 7;
    #pragma unroll
    for (int i = 0; i < 4; ++i) {
        const int r = q0 + ty * 4 + i;
        const float inv = 1.0f / l_run[i];
        float2 g2 = *(const float2*)&gh[((size_t)bh * NQ + r) * NC + tx * 2];
        float2 o2;
        o2.x = o_acc[i][0] * inv * g2.x;
        o2.y = o_acc[i][1] * inv * g2.y;
        *(float2*)&og[((size_t)(b * NQ + r)) * NHC + h * NC + tx * 2] = o2;
    }
}

extern "C" void kernel_launch(void* const* d_in, const int* in_sizes, int n_in,
                              void* d_out, int out_size, void* d_ws, size_t ws_size,
                              hipStream_t stream) {
    const float* q_x   = (const float*)d_in[0];
    const float* kv_x  = (const float*)d_in[1];
    const float* bias1 = (const float*)d_in[2];
    const float* bias2 = (const float*)d_in[3];
    const float* Wq    = (const float*)d_in[4];
    const float* Wk    = (const float*)d_in[5];
    const float* Wv    = (const float*)d_in[6];
    const float* Wg    = (const float*)d_in[7];
    const float* bg    = (const float*)d_in[8];
    const float* Wo    = (const float*)d_in[9];
    const float* bo    = (const float*)d_in[10];
    float* out = (float*)d_out;

    float* ws = (float*)d_ws;
    const size_t SEG = (size_t)NB * NH * NQ * NC;  // 1,048,576 floats (4 MB)
    float* qh = ws;
    float* kh = ws + SEG;
    float* vh = ws + 2 * SEG;
    float* gh = ws + 3 * SEG;
    float* og = ws + 4 * SEG;

    proj_kernel<<<dim3(64, 4, 4), 256, 0, stream>>>(q_x, kv_x, Wq, Wk, Wv, Wg, bg,
                                                    qh, kh, vh, gh);
    attn_kernel<<<dim3(512), 256, 0, stream>>>(qh, kh, vh, gh, bias1, bias2, og);
    out_proj_kernel<<<dim3(64, 4), 256, 0, stream>>>(og, Wo, bo, out);
}

// Round 12
// 589.349 us; speedup vs baseline: 1.0861x; 1.0861x over previous
//
#include <hip/hip_runtime.h>
#include <hip/hip_bf16.h>
#include <math.h>

#define NB 2
#define NQ 2048
#define NK 2048
#define NH 8
#define NC 32
#define NHC 256
#define NCIN 256

// Guide-verified gfx950 MFMA fragment types (short-based, NOT __bf16-based).
typedef short bf16x8 __attribute__((ext_vector_type(8)));
typedef float f32x4 __attribute__((ext_vector_type(4)));

__device__ __forceinline__ float redmax16(float v) {
    v = fmaxf(v, __shfl_xor(v, 1, 16));
    v = fmaxf(v, __shfl_xor(v, 2, 16));
    v = fmaxf(v, __shfl_xor(v, 4, 16));
    v = fmaxf(v, __shfl_xor(v, 8, 16));
    return v;
}
__device__ __forceinline__ float redsum16(float v) {
    v += __shfl_xor(v, 1, 16);
    v += __shfl_xor(v, 2, 16);
    v += __shfl_xor(v, 4, 16);
    v += __shfl_xor(v, 8, 16);
    return v;
}

// 64x64 tile fp32 GEMM body (projections are small; stay fp32-vector).
__device__ __forceinline__ void gemm_tile(const float* __restrict__ A,
                                          const float* __restrict__ W,
                                          float (*__restrict__ As)[68],
                                          float (*__restrict__ Bs)[68],
                                          float acc[4][4], int m0, int n0)
{
    const int t = threadIdx.x;
    const int ty = t >> 4, tx = t & 15;
    const int arow = t >> 2, acol = (t & 3) * 8;
    const int brow = t >> 3, bcol = (t & 7) * 8;

    for (int k0 = 0; k0 < NCIN; k0 += 32) {
        float4 a0 = *(const float4*)&A[(size_t)(m0 + arow) * NCIN + k0 + acol];
        float4 a1 = *(const float4*)&A[(size_t)(m0 + arow) * NCIN + k0 + acol + 4];
        float4 b0 = *(const float4*)&W[(size_t)(k0 + brow) * NHC + n0 + bcol];
        float4 b1 = *(const float4*)&W[(size_t)(k0 + brow) * NHC + n0 + bcol + 4];
        __syncthreads();
        As[acol + 0][arow] = a0.x; As[acol + 1][arow] = a0.y;
        As[acol + 2][arow] = a0.z; As[acol + 3][arow] = a0.w;
        As[acol + 4][arow] = a1.x; As[acol + 5][arow] = a1.y;
        As[acol + 6][arow] = a1.z; As[acol + 7][arow] = a1.w;
        *(float4*)&Bs[brow][bcol]     = b0;
        *(float4*)&Bs[brow][bcol + 4] = b1;
        __syncthreads();
        #pragma unroll
        for (int kk = 0; kk < 32; ++kk) {
            float4 av = *(const float4*)&As[kk][ty * 4];
            float4 bv = *(const float4*)&Bs[kk][tx * 4];
            float a_[4] = {av.x, av.y, av.z, av.w};
            float b_[4] = {bv.x, bv.y, bv.z, bv.w};
            #pragma unroll
            for (int i = 0; i < 4; ++i)
                #pragma unroll
                for (int j = 0; j < 4; ++j)
                    acc[i][j] = fmaf(a_[i], b_[j], acc[i][j]);
        }
    }
}

// Projections. mode 0: q (scaled, bf16 [bh][l][c]); 1: k (bf16 [bh][l][c]);
// 2: v (bf16 TRANSPOSED [bh][c][l] for PV B-frags); 3: g (sigmoid, fp32).
__global__ __launch_bounds__(256) void proj_kernel(
    const float* __restrict__ q_x, const float* __restrict__ kv_x,
    const float* __restrict__ Wq, const float* __restrict__ Wk,
    const float* __restrict__ Wv, const float* __restrict__ Wg,
    const float* __restrict__ bg,
    __hip_bfloat16* __restrict__ qh, __hip_bfloat16* __restrict__ kh,
    __hip_bfloat16* __restrict__ vt, float* __restrict__ gh)
{
    __shared__ float As[32][68];
    __shared__ float Bs[32][68];
    const int mode = blockIdx.z;
    const float* A = (mode == 0 || mode == 3) ? q_x : kv_x;
    const float* W = (mode == 0) ? Wq : (mode == 1) ? Wk : (mode == 2) ? Wv : Wg;
    const int m0 = blockIdx.x * 64, n0 = blockIdx.y * 64;

    float acc[4][4] = {};
    gemm_tile(A, W, As, Bs, acc, m0, n0);

    const int t = threadIdx.x, ty = t >> 4, tx = t & 15;
    const int m  = m0 + ty * 4;          // first of 4 rows (same b for all 4)
    const int b  = m >> 11, ll = m & 2047;
    const int n  = n0 + tx * 4;          // 4 cols, same head
    const int hh = n >> 5,  cc = n & 31;
    const int bhn = b * NH + hh;

    if (mode == 0 || mode == 1) {
        __hip_bfloat16* dst = (mode == 0) ? qh : kh;
        const float sc = (mode == 0) ? 0.17677669529663687f : 1.0f;
        #pragma unroll
        for (int i = 0; i < 4; ++i) {
            __hip_bfloat16 h4[4];
            #pragma unroll
            for (int j = 0; j < 4; ++j) h4[j] = __float2bfloat16(acc[i][j] * sc);
            *(uint2*)&dst[((size_t)bhn * NQ + ll + i) * NC + cc] = *(uint2*)h4;
        }
    } else if (mode == 2) {
        #pragma unroll
        for (int j = 0; j < 4; ++j) {
            __hip_bfloat16 h4[4];
            #pragma unroll
            for (int i = 0; i < 4; ++i) h4[i] = __float2bfloat16(acc[i][j]);
            *(uint2*)&vt[((size_t)bhn * NC + cc + j) * NQ + ll] = *(uint2*)h4;
        }
    } else {
        #pragma unroll
        for (int i = 0; i < 4; ++i) {
            float4 vv;
            vv.x = 1.0f / (1.0f + __expf(-(acc[i][0] + bg[n + 0])));
            vv.y = 1.0f / (1.0f + __expf(-(acc[i][1] + bg[n + 1])));
            vv.z = 1.0f / (1.0f + __expf(-(acc[i][2] + bg[n + 2])));
            vv.w = 1.0f / (1.0f + __expf(-(acc[i][3] + bg[n + 3])));
            *(float4*)&gh[((size_t)bhn * NQ + ll + i) * NC + cc] = vv;
        }
    }
}

// out = og @ Wo + bo, flat [B*Q, 256] (fp32).
__global__ __launch_bounds__(256) void out_proj_kernel(
    const float* __restrict__ og, const float* __restrict__ Wo,
    const float* __restrict__ bo, float* __restrict__ out)
{
    __shared__ float As[32][68];
    __shared__ float Bs[32][68];
    const int m0 = blockIdx.x * 64, n0 = blockIdx.y * 64;
    float acc[4][4] = {};
    gemm_tile(og, Wo, As, Bs, acc, m0, n0);
    const int t = threadIdx.x, ty = t >> 4, tx = t & 15;
    #pragma unroll
    for (int i = 0; i < 4; ++i) {
        const int m = m0 + ty * 4 + i;
        const int n = n0 + tx * 4;
        float4 bv = *(const float4*)&bo[n];
        float4 vv;
        vv.x = acc[i][0] + bv.x; vv.y = acc[i][1] + bv.y;
        vv.z = acc[i][2] + bv.z; vv.w = acc[i][3] + bv.w;
        *(float4*)&out[(size_t)m * NHC + n] = vv;
    }
}

// MFMA flash attention. Block = 64 q-rows of one (b,h); wave w owns 16 rows.
// No LDS staging for Q/K/V (direct global->frag loads; K/V stay L2-resident
// via the XCD-pinned (b,h) decode). Only P round-trips LDS, in a per-wave-
// private region -> ZERO __syncthreads in the k-loop.
// mfma_f32_16x16x32_bf16 layouts:
//   A: row=lane&15, k=8*(lane>>4)+e   B: col=lane&15, k=8*(lane>>4)+e
//   D: col=lane&15, row=4*(lane>>4)+r
__global__ __launch_bounds__(256) void attn_kernel(
    const __hip_bfloat16* __restrict__ qh, const __hip_bfloat16* __restrict__ kh,
    const __hip_bfloat16* __restrict__ vt, const float* __restrict__ gh,
    const float* __restrict__ b1, const float* __restrict__ b2,
    float* __restrict__ og)
{
    // P transpose buffer: [dbuf][wave][row 0..15][col 0..63 pad->88]
    __shared__ __align__(16) __hip_bfloat16 p_lds[2][4][16][88];

    const int wg  = blockIdx.x;
    const int xcd = wg & 7;
    const int idx = wg >> 3;
    const int bh  = xcd * 2 + (idx >> 5);  // 2 (b,h) per XCD for L2 K/V reuse
    const int q0  = (idx & 31) * 64;

    const int tid = threadIdx.x;
    const int w   = tid >> 6;
    const int l   = tid & 63;
    const int l15 = l & 15;
    const int g   = l >> 4;

    // Q A-frag, loaded once: row q0+16w+l15, k-chunk 8g
    const bf16x8 qa = *reinterpret_cast<const bf16x8*>(
        &qh[((size_t)bh * NQ + q0 + 16 * w + l15) * NC + 8 * g]);

    float m_run[4], l_run[4];
    f32x4 o_acc[2];
    #pragma unroll
    for (int r = 0; r < 4; ++r) { m_run[r] = -3.0e38f; l_run[r] = 0.0f; }
    o_acc[0] = (f32x4){0.f, 0.f, 0.f, 0.f};
    o_acc[1] = (f32x4){0.f, 0.f, 0.f, 0.f};

    const __hip_bfloat16* kbase = kh + (size_t)bh * NK * NC;
    const __hip_bfloat16* vbase = vt + (size_t)bh * NC * NK;
    const size_t brow = (size_t)bh * NQ + q0 + 16 * w;   // + 4g + r

    // bias tile 0 -> regs (register-double-buffered one iteration ahead)
    float nb1[4][4], nb2[4][4];
    #pragma unroll
    for (int r = 0; r < 4; ++r)
        #pragma unroll
        for (int t = 0; t < 4; ++t) {
            const size_t off = (brow + 4 * g + r) * (size_t)NK + 16 * t + l15;
            nb1[r][t] = b1[off];
            nb2[r][t] = b2[off];
        }

    for (int kt = 0; kt < NK / 64; ++kt) {
        const int kk0 = kt * 64;
        // K B-frags (QK col-tile t): K row kk0+16t+l15, c-chunk 8g.
        // Each instr = contiguous 1KB (16 rows x 64B) -> perfectly coalesced.
        bf16x8 kf[4];
        #pragma unroll
        for (int t = 0; t < 4; ++t)
            kf[t] = *reinterpret_cast<const bf16x8*>(
                &kbase[(size_t)(kk0 + 16 * t + l15) * NC + 8 * g]);
        // V B-frags (PV): c-col 16n+l15, k = kk0+32ks+8g
        bf16x8 vf[2][2];
        #pragma unroll
        for (int n = 0; n < 2; ++n)
            #pragma unroll
            for (int ks = 0; ks < 2; ++ks)
                vf[n][ks] = *reinterpret_cast<const bf16x8*>(
                    &vbase[(size_t)(16 * n + l15) * NK + kk0 + 32 * ks + 8 * g]);

        // QK^T: S quadrant cols 16t..16t+15
        f32x4 dqk[4];
        #pragma unroll
        for (int t = 0; t < 4; ++t)
            dqk[t] = __builtin_amdgcn_mfma_f32_16x16x32_bf16(
                qa, kf[t], (f32x4){0.f, 0.f, 0.f, 0.f}, 0, 0, 0);

        // bias + online softmax (row = 4g+r, stats across the 16-lane group)
        float p[4][4], resc[4];
        #pragma unroll
        for (int r = 0; r < 4; ++r) {
            float s0 = dqk[0][r] + nb1[r][0] + nb2[r][0];
            float s1 = dqk[1][r] + nb1[r][1] + nb2[r][1];
            float s2 = dqk[2][r] + nb1[r][2] + nb2[r][2];
            float s3 = dqk[3][r] + nb1[r][3] + nb2[r][3];
            float tm = redmax16(fmaxf(fmaxf(s0, s1), fmaxf(s2, s3)));
            const float mn = fmaxf(m_run[r], tm);
            resc[r] = __expf(m_run[r] - mn);
            p[r][0] = __expf(s0 - mn);
            p[r][1] = __expf(s1 - mn);
            p[r][2] = __expf(s2 - mn);
            p[r][3] = __expf(s3 - mn);
            const float ts = redsum16(p[r][0] + p[r][1] + p[r][2] + p[r][3]);
            l_run[r] = l_run[r] * resc[r] + ts;
            m_run[r] = mn;
        }
        #pragma unroll
        for (int n = 0; n < 2; ++n)
            #pragma unroll
            for (int r = 0; r < 4; ++r)
                o_acc[n][r] *= resc[r];

        // P -> LDS (bf16, D-layout scatter; per-wave-private region).
        // Bank check: banks for (g,l15) spread over {0-7,12-19,24-31,4-11}
        // per g-group with the 88-pad -> ~2-way worst case (free, m136).
        const int pb = kt & 1;
        #pragma unroll
        for (int r = 0; r < 4; ++r)
            #pragma unroll
            for (int t = 0; t < 4; ++t)
                p_lds[pb][w][4 * g + r][16 * t + l15] = __float2bfloat16(p[r][t]);

        // prefetch next bias tile (consumed next iteration -> one full
        // HBM-bound iteration of latency cover)
        const int nk0 = (kt + 1 < NK / 64) ? kk0 + 64 : 0;
        #pragma unroll
        for (int r = 0; r < 4; ++r)
            #pragma unroll
            for (int t = 0; t < 4; ++t) {
                const size_t off = (brow + 4 * g + r) * (size_t)NK + nk0 + 16 * t + l15;
                nb1[r][t] = b1[off];
                nb2[r][t] = b2[off];
            }

        asm volatile("s_waitcnt lgkmcnt(0)" ::: "memory");
        __builtin_amdgcn_sched_barrier(0);

        // P A-frags: row l15, k-chunks 8g and 32+8g
        const bf16x8 pa0 = *reinterpret_cast<const bf16x8*>(&p_lds[pb][w][l15][8 * g]);
        const bf16x8 pa1 = *reinterpret_cast<const bf16x8*>(&p_lds[pb][w][l15][32 + 8 * g]);

        o_acc[0] = __builtin_amdgcn_mfma_f32_16x16x32_bf16(pa0, vf[0][0], o_acc[0], 0, 0, 0);
        o_acc[0] = __builtin_amdgcn_mfma_f32_16x16x32_bf16(pa1, vf[0][1], o_acc[0], 0, 0, 0);
        o_acc[1] = __builtin_amdgcn_mfma_f32_16x16x32_bf16(pa0, vf[1][0], o_acc[1], 0, 0, 0);
        o_acc[1] = __builtin_amdgcn_mfma_f32_16x16x32_bf16(pa1, vf[1][1], o_acc[1], 0, 0, 0);
    }

    // epilogue: normalize, gate, store (D-layout: row 4g+r, col 16n+l15)
    const int b = bh >> 3, h = bh & 7;
    #pragma unroll
    for (int r = 0; r < 4; ++r) {
        const int grow = q0 + 16 * w + 4 * g + r;
        const float inv = 1.0f / l_run[r];
        #pragma unroll
        for (int n = 0; n < 2; ++n) {
            const int c = 16 * n + l15;
            const float gate = gh[((size_t)bh * NQ + grow) * NC + c];
            og[((size_t)(b * NQ + grow)) * NHC + h * NC + c] = o_acc[n][r] * inv * gate;
        }
    }
}

extern "C" void kernel_launch(void* const* d_in, const int* in_sizes, int n_in,
                              void* d_out, int out_size, void* d_ws, size_t ws_size,
                              hipStream_t stream) {
    const float* q_x   = (const float*)d_in[0];
    const float* kv_x  = (const float*)d_in[1];
    const float* bias1 = (const float*)d_in[2];
    const float* bias2 = (const float*)d_in[3];
    const float* Wq    = (const float*)d_in[4];
    const float* Wk    = (const float*)d_in[5];
    const float* Wv    = (const float*)d_in[6];
    const float* Wg    = (const float*)d_in[7];
    const float* bg    = (const float*)d_in[8];
    const float* Wo    = (const float*)d_in[9];
    const float* bo    = (const float*)d_in[10];
    float* out = (float*)d_out;

    char* ws = (char*)d_ws;
    const size_t NTOK = (size_t)NB * NH * NQ * NC;       // 1M elements
    __hip_bfloat16* qh = (__hip_bfloat16*)(ws);                   // 2 MB
    __hip_bfloat16* kh = (__hip_bfloat16*)(ws + 2 * NTOK);        // 2 MB
    __hip_bfloat16* vt = (__hip_bfloat16*)(ws + 4 * NTOK);        // 2 MB
    float*          gh = (float*)         (ws + 6 * NTOK);        // 4 MB
    float*          og = (float*)         (ws + 10 * NTOK);       // 4 MB

    proj_kernel<<<dim3(64, 4, 4), 256, 0, stream>>>(q_x, kv_x, Wq, Wk, Wv, Wg, bg,
                                                    qh, kh, vt, gh);
    attn_kernel<<<dim3(512), 256, 0, stream>>>(qh, kh, vt, gh, bias1, bias2, og);
    out_proj_kernel<<<dim3(64, 4), 256, 0, stream>>>(og, Wo, bo, out);
}